// Round 13
// baseline (210.253 us; speedup 1.0000x reference)
//
#include <hip/hip_runtime.h>
#include <hip/hip_bf16.h>

typedef __attribute__((ext_vector_type(8))) short short8;
typedef __attribute__((ext_vector_type(4))) float f32x4;

#define MFMA16(a,b,c) __builtin_amdgcn_mfma_f32_16x16x32_bf16((a),(b),(c),0,0,0)

// Counted waits + raw barrier. NEVER drain vmcnt(0) mid-loop (T4).
#define WAITVM(N) asm volatile("s_waitcnt vmcnt(" #N ")" ::: "memory")
#define BAR()     asm volatile("s_barrier" ::: "memory")

constexpr int Tt = 1705;          // (L+1) + L*16 + L*196
constexpr int Tp = 1792;          // padded to 28*64
constexpr int NKT_ALL = 28;       // Tp/64 key tiles
constexpr int NH = 12, HD = 64, Bb = 4, C_ = 768;
constexpr int M_  = Bb * Tt;      // 6820
constexpr int Mp  = 6912;         // 27*256 = 54*128
constexpr int NQT = 14;           // 128-row q-tiles
constexpr int NCH = 4;            // key-range chunks per q-tile (split-K flash)
constexpr float QSCALE = 0.18033688011116016f;   // (1/8) * log2(e)

static_assert(Mp % 128 == 0 && (3 * C_) % 128 == 0, "128-tile grid");

__device__ __forceinline__ void gl16(const void* g, void* l) {
  __builtin_amdgcn_global_load_lds((const __attribute__((address_space(1))) void*)g,
                                   (__attribute__((address_space(3))) void*)l, 16, 0, 0);
}

// raw v_exp_f32 (no libm fixup). Inputs bounded; -1e30 -> 0.
__device__ __forceinline__ float ex2(float x) {
  float r; asm("v_exp_f32 %0, %1" : "=v"(r) : "v"(x)); return r;
}

// frame id of token t (t<1705). Action tokens (t<9) return their index.
__device__ __forceinline__ int frame_of(int t) {
  return t < 9 ? t : (t < 137 ? ((t - 9) >> 4) : ((t - 137) / 196));
}

// key-limit for a 16-row span starting at a (rows [a, a+15])
__device__ __forceinline__ int lim16(int a) {
  if (a >= Tt) return 0;
  int bnd = min(a + 15, Tt - 1);
  int fmax = (a == 0) ? 8 : frame_of(min(bnd, a < 137 ? 136 : bnd));
  return (fmax >= 8) ? Tt : 137 + (fmax + 1) * 196;
}

// ---------------- fused prep: conv x->bf16 + both W transposes ---------------
constexpr int PREP_CONV = Mp * C_ / 4 / 256;              // 5184 blocks
constexpr int PREP_TA   = (C_ / 32) * (3 * C_ / 32);      // 1728 blocks
constexpr int PREP_TB   = (C_ / 32) * (C_ / 32);          // 576 blocks

__global__ __launch_bounds__(256) void k_prep(const float* __restrict__ x,
                                              __hip_bfloat16* __restrict__ xb,
                                              const float* __restrict__ Wa,
                                              __hip_bfloat16* __restrict__ wat,
                                              const float* __restrict__ Wp,
                                              __hip_bfloat16* __restrict__ wpt) {
  __shared__ float tile[32][33];
  const int bid = blockIdx.x, tid = threadIdx.x;
  if (bid < PREP_CONV) {                        // ---- x fp32 -> bf16 (padded)
    int i = bid * 256 + tid;
    float4 v = make_float4(0.f, 0.f, 0.f, 0.f);
    if (i * 4 < M_ * C_) v = ((const float4*)x)[i];
    __hip_bfloat16 o0 = __float2bfloat16(v.x), o1 = __float2bfloat16(v.y),
                   o2 = __float2bfloat16(v.z), o3 = __float2bfloat16(v.w);
    ushort4 u = make_ushort4(*(unsigned short*)&o0, *(unsigned short*)&o1,
                             *(unsigned short*)&o2, *(unsigned short*)&o3);
    ((ushort4*)xb)[i] = u;
    return;
  }
  const float* src; __hip_bfloat16* dst; int N, bid2;
  if (bid < PREP_CONV + PREP_TA) { bid2 = bid - PREP_CONV; src = Wa; dst = wat; N = 3 * C_; }
  else                           { bid2 = bid - PREP_CONV - PREP_TA; src = Wp; dst = wpt; N = C_; }
  const int K = C_;
  int kb = (bid2 % (C_ / 32)) * 32, nb = (bid2 / (C_ / 32)) * 32;
  int tx = tid & 31, ty = tid >> 5;
  for (int i = 0; i < 4; i++)
    tile[ty + i * 8][tx] = src[(size_t)(kb + ty + i * 8) * N + nb + tx];
  __syncthreads();
  for (int i = 0; i < 4; i++)
    dst[(size_t)(nb + ty + i * 8) * K + kb + tx] = __float2bfloat16(tile[tx][ty + i * 8]);
}

// ---------------- 128x128-tile 4-wave qkv GEMM, 4-deep pipeline --------------
// R13 = R12 with the q-epilogue bug fixed (R12 iterated the q path in TOKEN
// space over [0,128) — batch-crossing tiles with ts>=128 never wrote their b0
// segment). Now iterates LOCAL rows lr, token t = lr - rb. K/V paths were
// already token-space-correct (element-verified: K t=17,d=37 -> i=193/s=5;
// V t=49,d=23 -> i=199/s=5).
// Hypothesis under test (attn lesson R3 vs R4-R6): 128² @ 64KB LDS = 2
// INDEPENDENT blocks/CU; when one block drains at its barrier the other's
// waves issue MFMA (256² was 1 block/CU -> nothing to issue during drains,
// MfmaUtil pinned 13-15% across R0-R11 regardless of pipeline depth).
__global__ __launch_bounds__(256) void k_gemm_qkv(const __hip_bfloat16* __restrict__ xb,
                                                  const __hip_bfloat16* __restrict__ wat,
                                                  __hip_bfloat16* __restrict__ q,
                                                  __hip_bfloat16* __restrict__ kpk,
                                                  __hip_bfloat16* __restrict__ vpk) {
  __shared__ __hip_bfloat16 smem[32768];       // 64 KB: 4 stage slots / epi
  const int tid = threadIdx.x;                 // 0..255, 4 waves
  const int lane = tid & 63, w = tid >> 6;
  const int wr = w >> 1, wc = w & 1;           // wave -> (row-half, col-half)
  const int l16 = lane & 15, grp = lane >> 4;
  const int m0 = blockIdx.x * 128, n0 = blockIdx.y * 128;
  constexpr int NT = C_ / 32;                  // 24 K-tiles
  constexpr int ES = 132;                      // epi LDS row stride (elems)

  // stage K-tile t into slot bb (A 128x32 + B 128x32; 4 gl16/thread)
  auto stage = [&](int t, int bb) {
    int k0 = t * 32;
    __hip_bfloat16* As = smem + bb * 4096;
    __hip_bfloat16* Bs = smem + 16384 + bb * 4096;
    for (int p = 0; p < 2; p++) {
      int idx = p * 256 + tid;                 // [0,512): row*4 + phys-chunk
      int row = idx >> 2;
      int c8 = (idx & 3) ^ ((row >> 1) & 3);   // proven swizzle (0 conflicts)
      gl16(xb  + (size_t)(m0 + row) * C_ + k0 + c8 * 8, As + idx * 8);
      gl16(wat + (size_t)(n0 + row) * C_ + k0 + c8 * 8, Bs + idx * 8);
    }
  };

  f32x4 acc[4][4];
  for (int i = 0; i < 4; i++)
    for (int j = 0; j < 4; j++) { f32x4 z = {0.f,0.f,0.f,0.f}; acc[i][j] = z; }

  stage(0, 0); stage(1, 1); stage(2, 2);

  for (int t = 0; t < NT; t++) {
    if (t + 3 < NT) stage(t + 3, (t + 3) & 3);
    int rem = NT - 1 - t;                      // tiles staged beyond t
    if (rem >= 3)      WAITVM(12);
    else if (rem == 2) WAITVM(8);
    else if (rem == 1) WAITVM(4);
    else               WAITVM(0);
    BAR();                                     // tile t visible to all waves
    const __hip_bfloat16* Ac = smem + (t & 3) * 4096;
    const __hip_bfloat16* Bc = smem + 16384 + (t & 3) * 4096;
    short8 afr[4], bfr[4];
    for (int nj = 0; nj < 4; nj++) {
      int row = wc * 64 + nj * 16 + l16;
      bfr[nj] = *(const short8*)(Bc + row * 32 + ((grp ^ ((row >> 1) & 3)) * 8));
    }
    for (int mi = 0; mi < 4; mi++) {
      int row = wr * 64 + mi * 16 + l16;
      afr[mi] = *(const short8*)(Ac + row * 32 + ((grp ^ ((row >> 1) & 3)) * 8));
    }
    __builtin_amdgcn_s_setprio(1);
    for (int mi = 0; mi < 4; mi++)
      for (int nj = 0; nj < 4; nj++)
        acc[mi][nj] = MFMA16(afr[mi], bfr[nj], acc[mi][nj]);
    __builtin_amdgcn_s_setprio(0);
    BAR();                                     // readers of slot t&3 done
  }

  // ---------------- coalesced epilogue (R9 pattern, 128-wide tile) ----------
  const int which = n0 / C_;                   // 0=q, 1=k, 2=v (block-uniform)
  const int cbase = n0 - which * C_;           // 0..640 step 128
  const int h0 = cbase >> 6;                   // 2 heads: h0, h0+1
  const float scale = (which == 0) ? QSCALE : 1.0f;
  const int b0 = m0 / Tt;
  const int b1 = min((m0 + 127) / Tt, Bb - 1);
  __hip_bfloat16* epi = smem;                  // [128][ES] tile (34 KB)

  // phase A: all waves dump acc into epi (single pass)
  for (int mi = 0; mi < 4; mi++)
    for (int nj = 0; nj < 4; nj++) {
      int row = wr * 64 + mi * 16 + grp * 4;
      int col = wc * 64 + nj * 16 + l16;
      #pragma unroll
      for (int r = 0; r < 4; r++)
        epi[(row + r) * ES + col] = __float2bfloat16(acc[mi][nj][r] * scale);
    }
  __syncthreads();

  // phase B: destination-ordered coalesced writes
  for (int b = b0; b <= b1; b++) {
    int ts = max(0, m0 - b * Tt), te = min(Tt, m0 + 128 - b * Tt);
    if (ts >= te) continue;
    const int rb = b * Tt - m0;                // local row = rb + token
    if (which == 0) {
      for (int hh = 0; hh < 2; hh++) {
        int bh = b * NH + h0 + hh;
        __hip_bfloat16* qd = q + (size_t)bh * Tp * HD;
        for (int it = 0; it < 4; it++) {
          int i = it * 256 + tid;              // [0,1024): lr=i>>3, d0=(i&7)*8
          int lr = i >> 3, d0 = (i & 7) * 8;   // lr = LOCAL row (R12 bug: was
          int t = lr - rb;                     // treated as token index)
          if (t >= ts && t < te) {
            int ad = lr * ES + hh * 64 + d0;
            union { short8 v; ushort4 h[2]; } u;
            u.h[0] = *(const ushort4*)(epi + ad);
            u.h[1] = *(const ushort4*)(epi + ad + 4);
            *(short8*)(qd + (size_t)t * HD + d0) = u.v;
          }
        }
      }
    } else if (which == 1) {
      for (int kt = ts >> 6; kt <= (te - 1) >> 6; kt++)
        for (int hh = 0; hh < 2; hh++) {
          int bh = b * NH + h0 + hh;
          short8* kd = (short8*)(kpk + ((size_t)bh * NKT_ALL + kt) * 4096);
          for (int it = 0; it < 2; it++) {
            int i = it * 256 + tid;            // [0,512) short8 index
            int tin = ((i >> 7) << 4) + (i & 15);
            int d0 = ((i >> 6) & 1) * 32 + ((i >> 4) & 3) * 8;
            int t = kt * 64 + tin;             // token index
            if (t >= ts && t < te) {
              int ad = (rb + t) * ES + hh * 64 + d0;
              union { short8 v; ushort4 h[2]; } u;
              u.h[0] = *(const ushort4*)(epi + ad);
              u.h[1] = *(const ushort4*)(epi + ad + 4);
              kd[i] = u.v;
            }
          }
        }
    } else {
      for (int kt = ts >> 6; kt <= (te - 1) >> 6; kt++)
        for (int hh = 0; hh < 2; hh++) {
          int bh = b * NH + h0 + hh;
          __hip_bfloat16* vd = vpk + ((size_t)bh * NKT_ALL + kt) * 4096;
          bool full = (kt * 64 >= ts) && (kt * 64 + 64 <= te);
          for (int it = 0; it < 2; it++) {
            int i = it * 256 + tid;            // [0,512) short8 index
            int kb2 = (i >> 6) & 1, gg = (i >> 4) & 3;
            int d = ((i >> 7) << 4) + (i & 15);
            if (full) {
              short8 v;
              #pragma unroll
              for (int s = 0; s < 8; s++) {
                int tin = kb2 * 32 + gg * 4 + (s & 3) + ((s >> 2) << 4);
                v[s] = *(const short*)(epi + (rb + kt * 64 + tin) * ES + hh * 64 + d);
              }
              ((short8*)vd)[i] = v;
            } else {
              #pragma unroll
              for (int s = 0; s < 8; s++) {
                int tin = kb2 * 32 + gg * 4 + (s & 3) + ((s >> 2) << 4);
                int t = kt * 64 + tin;
                if (t >= ts && t < te)
                  vd[(size_t)i * 8 + s] = epi[(rb + t) * ES + hh * 64 + d];
              }
            }
          }
        }
    }
  }
}

// ---------------- 128x128-tile proj GEMM, 4-deep pipeline --------------------
// R10 form. FROZEN.
__global__ __launch_bounds__(256) void k_gemm_proj128(const __hip_bfloat16* __restrict__ A,
                                                      const __hip_bfloat16* __restrict__ Bt,
                                                      float* __restrict__ out) {
  __shared__ __hip_bfloat16 As[4][128 * 32], Bs[4][128 * 32];   // 64 KB
  const int tid = threadIdx.x;                 // 0..255, 4 waves
  const int lane = tid & 63, w = tid >> 6;
  const int wr = w >> 1, wc = w & 1;           // wave -> (row-half, col-half)
  const int l16 = lane & 15, grp = lane >> 4;
  const int m0 = blockIdx.x * 128, n0 = blockIdx.y * 128;
  constexpr int NT = C_ / 32;                  // 24 K-tiles

  auto stage = [&](int t, int bb) {
    int k0 = t * 32;
    for (int p = 0; p < 2; p++) {
      int idx = p * 256 + tid;                 // [0,512): row*4 + phys-chunk
      int row = idx >> 2;
      int c8 = (idx & 3) ^ ((row >> 1) & 3);   // proven swizzle (0 conflicts)
      gl16(A  + (size_t)(m0 + row) * C_ + k0 + c8 * 8, &As[bb][idx * 8]);
      gl16(Bt + (size_t)(n0 + row) * C_ + k0 + c8 * 8, &Bs[bb][idx * 8]);
    }
  };

  f32x4 acc[4][4];
  for (int i = 0; i < 4; i++)
    for (int j = 0; j < 4; j++) { f32x4 z = {0.f,0.f,0.f,0.f}; acc[i][j] = z; }

  stage(0, 0); stage(1, 1); stage(2, 2);

  for (int t = 0; t < NT; t++) {
    if (t + 3 < NT) stage(t + 3, (t + 3) & 3);
    int rem = NT - 1 - t;
    if (rem >= 3)      WAITVM(12);
    else if (rem == 2) WAITVM(8);
    else if (rem == 1) WAITVM(4);
    else               WAITVM(0);
    BAR();
    const __hip_bfloat16* Ac = As[t & 3];
    const __hip_bfloat16* Bc = Bs[t & 3];
    short8 afr[4], bfr[4];
    for (int nj = 0; nj < 4; nj++) {
      int row = wc * 64 + nj * 16 + l16;
      bfr[nj] = *(const short8*)(Bc + row * 32 + ((grp ^ ((row >> 1) & 3)) * 8));
    }
    for (int mi = 0; mi < 4; mi++) {
      int row = wr * 64 + mi * 16 + l16;
      afr[mi] = *(const short8*)(Ac + row * 32 + ((grp ^ ((row >> 1) & 3)) * 8));
    }
    __builtin_amdgcn_s_setprio(1);
    for (int mi = 0; mi < 4; mi++)
      for (int nj = 0; nj < 4; nj++)
        acc[mi][nj] = MFMA16(afr[mi], bfr[nj], acc[mi][nj]);
    __builtin_amdgcn_s_setprio(0);
    BAR();
  }

  for (int mi = 0; mi < 4; mi++)
    for (int r = 0; r < 4; r++) {
      int m = m0 + wr * 64 + mi * 16 + grp * 4 + r;
      if (m >= M_) continue;
      for (int nj = 0; nj < 4; nj++)
        out[(size_t)m * C_ + n0 + wc * 64 + nj * 16 + l16] = acc[mi][nj][r];
    }
}

// ---------------- barrier-free, LDS-free split-K flash attention -------------
// FROZEN (R3 body + QLUT). R4-R7 proved every pipelining/remap/occupancy
// variant regresses; attn lives on TLP at VGPR 84, plateau ~55 µs.
union S8u { short8 v; struct { unsigned long long lo, hi; } q; unsigned u[4]; };

__device__ __forceinline__ unsigned pack2bf(float a, float b) {
  union { __hip_bfloat162 h; unsigned u; } cv;
  cv.h = __float22bfloat162_rn(make_float2(a, b));
  return cv.u;
}

__constant__ int QLUT[NQT] = {0, 1, 11, 12, 13, 10, 8, 9, 7, 5, 6, 4, 2, 3};

__global__ __launch_bounds__(256, 2) void k_attn(const __hip_bfloat16* __restrict__ q,
                                                 const __hip_bfloat16* __restrict__ kpk,
                                                 const __hip_bfloat16* __restrict__ vpk,
                                                 __hip_bfloat16* __restrict__ Opart,
                                                 float* __restrict__ lpart) {
  const int tid = threadIdx.x, lane = tid & 63, w = tid >> 6;
  const int l16 = lane & 15, grp = lane >> 4;
  // XCD-aware decode: id = (bh&7) + 8*(cq + 56*(bh>>3)); longest-first qt
  const int id = blockIdx.x;
  const int xslot = id & 7, rr_ = id >> 3;
  const int bh = xslot + 8 * (rr_ / 56);
  const int cqs = rr_ % 56;                     // qslot*NCH + ch
  const int qt = QLUT[cqs >> 2], ch = cqs & (NCH - 1);
  const int cq = qt * NCH + ch;                 // actual output block index
  const int t0q = qt * 128;
  const __hip_bfloat16* qb = q + (size_t)bh * Tp * HD;

  int lim[2], Cmn[2], Ath[2], Bth[2], Cth[2];
  for (int g = 0; g < 2; g++) {
    int a = t0q + w * 32 + g * 16;
    lim[g] = lim16(a);
    int fqmn, fql;
    if (a >= Tt) { fqmn = 8; fql = 8; }
    else {
      int bnd = min(a + 15, Tt - 1);
      fqmn = min(frame_of(a), frame_of(bnd));
      int t = a + l16;
      fql = (t >= Tt) ? 8 : frame_of(t);
    }
    Cmn[g] = min(137 + 196 * (fqmn + 1), Tt);   // wave-wide full-tile bound
    Ath[g] = fql + 2;                            // action keys: key < A
    Bth[g] = 9 + 16 * (fql + 1);                 // tactile keys: key < B
    Cth[g] = min(137 + 196 * (fql + 1), Tt);     // image keys: key < C
  }
  int limw = max(lim[0], lim[1]);
  int nktw = (limw + 63) >> 6;                  // this wave's needed tiles
  int k0t = (ch * nktw) >> 2;                   // balanced split
  int k1t = ((ch + 1) * nktw) >> 2;

  // Q fragments (once per wave)
  short8 qa[2][2];
  for (int g = 0; g < 2; g++) {
    const __hip_bfloat16* qr = qb + (size_t)(t0q + w * 32 + g * 16 + l16) * HD + grp * 8;
    qa[g][0] = *(const short8*)(qr);
    qa[g][1] = *(const short8*)(qr + 32);
  }
  f32x4 o[2][4];
  for (int g = 0; g < 2; g++)
    for (int jt = 0; jt < 4; jt++) { f32x4 z = {0.f,0.f,0.f,0.f}; o[g][jt] = z; }
  f32x4 ps[2];
  { f32x4 z = {0.f,0.f,0.f,0.f}; ps[0] = z; ps[1] = z; }

  const short8* kbase = (const short8*)(kpk + (size_t)bh * NKT_ALL * 4096);
  const short8* vbase = (const short8*)(vpk + (size_t)bh * NKT_ALL * 4096);

  for (int kt = k0t; kt < k1t; kt++) {
    const int t0k = kt * 64;
    const short8* kp = kbase + (size_t)kt * 512;
    const short8* vp = vbase + (size_t)kt * 512;
    short8 kf[4][2], vf[4][2];
    for (int j = 0; j < 4; j++)
      for (int hh = 0; hh < 2; hh++) kf[j][hh] = kp[(j * 2 + hh) * 64 + lane];
    for (int jt = 0; jt < 4; jt++)
      for (int kb2 = 0; kb2 < 2; kb2++) vf[jt][kb2] = vp[(jt * 2 + kb2) * 64 + lane];

    f32x4 s[2][4];
    for (int j = 0; j < 4; j++) {               // S^T = K * Q^T
      f32x4 z = {0.f,0.f,0.f,0.f};
      s[0][j] = MFMA16(kf[j][0], qa[0][0], z);
      s[0][j] = MFMA16(kf[j][1], qa[0][1], s[0][j]);
      s[1][j] = MFMA16(kf[j][0], qa[1][0], z);
      s[1][j] = MFMA16(kf[j][1], qa[1][1], s[1][j]);
    }

    bool act0 = t0k < lim[0], act1 = t0k < lim[1];
    bool fullk = (t0k + 64 <= Tt);
    S8u pf[2][2];
    for (int g = 0; g < 2; g++) {
      bool act = g == 0 ? act0 : act1;
      if (!act) continue;                       // wave-uniform
      bool needm = !(fullk && (t0k >= 192 ? (t0k + 64) <= Cmn[g] : Cmn[g] >= Tt));
      if (needm) {                              // threshold-compare mask
        for (int j = 0; j < 4; j++)
          for (int r = 0; r < 4; r++) {
            int key = t0k + j * 16 + grp * 4 + r;
            int thr = key < 9 ? Ath[g] : (key < 137 ? Bth[g] : Cth[g]);
            if (key >= thr) s[g][j][r] = -1e30f;
          }
      }
      f32x4 p[4];
      for (int j = 0; j < 4; j++)
        for (int r = 0; r < 4; r++) p[j][r] = ex2(s[g][j][r]);
      ps[g] += (p[0] + p[1]) + (p[2] + p[3]);   // deferred reduction
      pf[g][0].u[0] = pack2bf(p[0][0], p[0][1]);
      pf[g][0].u[1] = pack2bf(p[0][2], p[0][3]);
      pf[g][0].u[2] = pack2bf(p[1][0], p[1][1]);
      pf[g][0].u[3] = pack2bf(p[1][2], p[1][3]);
      pf[g][1].u[0] = pack2bf(p[2][0], p[2][1]);
      pf[g][1].u[1] = pack2bf(p[2][2], p[2][3]);
      pf[g][1].u[2] = pack2bf(p[3][0], p[3][1]);
      pf[g][1].u[3] = pack2bf(p[3][2], p[3][3]);
    }

    for (int jt = 0; jt < 4; jt++)              // O^T += V^T * P^T
      for (int kb2 = 0; kb2 < 2; kb2++) {
        if (act0) o[0][jt] = MFMA16(vf[jt][kb2], pf[0][kb2].v, o[0][jt]);
        if (act1) o[1][jt] = MFMA16(vf[jt][kb2], pf[1][kb2].v, o[1][jt]);
      }
  }

  // final softmax-denominator reduction (once, not per tile)
  float lr[2];
  for (int g = 0; g < 2; g++) {
    float sum = (ps[g][0] + ps[g][1]) + (ps[g][2] + ps[g][3]);
    sum += __shfl_xor(sum, 16);
    sum += __shfl_xor(sum, 32);
    lr[g] = sum;
  }

  // epilogue: unnormalized bf16 partials (always written, zeros if empty)
  const int blk = bh * (NQT * NCH) + cq;
  __hip_bfloat16* op = Opart + (size_t)blk * (128 * 64);
  for (int g = 0; g < 2; g++) {
    int row = w * 32 + g * 16 + l16;
    for (int jt = 0; jt < 4; jt++) {
      unsigned p01 = pack2bf(o[g][jt][0], o[g][jt][1]);
      unsigned p23 = pack2bf(o[g][jt][2], o[g][jt][3]);
      ushort4 u;
      u.x = p01 & 0xffff; u.y = p01 >> 16; u.z = p23 & 0xffff; u.w = p23 >> 16;
      *(ushort4*)(op + row * 64 + jt * 16 + grp * 4) = u;
    }
    if (grp == 0) lpart[(size_t)blk * 128 + w * 32 + g * 16 + l16] = lr[g];
  }
}

// sum NCH chunk partials, normalize, write y bf16
__global__ __launch_bounds__(256) void k_combine(const __hip_bfloat16* __restrict__ Opart,
                                                 const float* __restrict__ lpart,
                                                 __hip_bfloat16* __restrict__ y) {
  const int tid = threadIdx.x;
  const int qt = blockIdx.x, bh = blockIdx.y;
  const int b = bh / NH, h = bh - b * NH;
  const int t0q = qt * 128;
  const int blk0 = bh * (NQT * NCH) + qt * NCH;
  __shared__ float ls[128];
  if (tid < 128) {
    float s = 0.f;
    for (int c = 0; c < NCH; c++) s += lpart[(size_t)(blk0 + c) * 128 + tid];
    ls[tid] = (s > 0.f) ? 1.0f / s : 0.f;
  }
  __syncthreads();
  for (int it = 0; it < 4; it++) {
    int e8 = it * 256 + tid;                     // 8-elem group in [0,1024)
    int e = e8 * 8;
    int row = e >> 6, d = e & 63;
    int t = t0q + row;
    if (t >= Tt) continue;
    float acc[8] = {0,0,0,0,0,0,0,0};
    for (int c = 0; c < NCH; c++) {
      short8 vv = *(const short8*)(Opart + (size_t)(blk0 + c) * (128 * 64) + e);
      for (int i = 0; i < 8; i++) {
        union { unsigned u; float f; } cv;
        cv.u = ((unsigned)(unsigned short)vv[i]) << 16;
        acc[i] += cv.f;
      }
    }
    float rinv = ls[row];
    short8 outv;
    for (int i = 0; i < 8; i += 2) {
      unsigned p = pack2bf(acc[i] * rinv, acc[i + 1] * rinv);
      outv[i] = (short)(p & 0xffff);
      outv[i + 1] = (short)(p >> 16);
    }
    *(short8*)(y + (size_t)(b * Tt + t) * C_ + h * 64 + d) = outv;
  }
}

extern "C" void kernel_launch(void* const* d_in, const int* in_sizes, int n_in,
                              void* d_out, int out_size, void* d_ws, size_t ws_size,
                              hipStream_t stream) {
  const float* x  = (const float*)d_in[0];
  const float* Wa = (const float*)d_in[1];
  const float* Wp = (const float*)d_in[2];
  float* out = (float*)d_out;

  char* ws = (char*)d_ws;
  size_t off = 0;
  auto alloc = [&](size_t bytes) { size_t r = off; off += (bytes + 255) & ~(size_t)255; return r; };
  __hip_bfloat16* xb  = (__hip_bfloat16*)(ws + alloc((size_t)Mp * C_ * 2));
  __hip_bfloat16* wat = (__hip_bfloat16*)(ws + alloc((size_t)3 * C_ * C_ * 2));
  __hip_bfloat16* wpt = (__hip_bfloat16*)(ws + alloc((size_t)C_ * C_ * 2));
  __hip_bfloat16* qb  = (__hip_bfloat16*)(ws + alloc((size_t)Bb * NH * Tp * HD * 2));
  __hip_bfloat16* kpk = (__hip_bfloat16*)(ws + alloc((size_t)Bb * NH * NKT_ALL * 4096 * 2));
  __hip_bfloat16* vpk = (__hip_bfloat16*)(ws + alloc((size_t)Bb * NH * NKT_ALL * 4096 * 2));
  __hip_bfloat16* yb  = (__hip_bfloat16*)(ws + alloc((size_t)Mp * C_ * 2));
  __hip_bfloat16* Opart = (__hip_bfloat16*)(ws + alloc((size_t)Bb * NH * NQT * NCH * 128 * 64 * 2));
  float*          lpart = (float*)(ws + alloc((size_t)Bb * NH * NQT * NCH * 128 * 4));

  k_prep<<<PREP_CONV + PREP_TA + PREP_TB, 256, 0, stream>>>(x, xb, Wa, wat, Wp, wpt);
  k_gemm_qkv<<<dim3(Mp / 128, 3 * C_ / 128), 256, 0, stream>>>(xb, wat, qb, kpk, vpk);
  k_attn<<<dim3(Bb * NH * NQT * NCH), 256, 0, stream>>>(qb, kpk, vpk, Opart, lpart);
  k_combine<<<dim3(NQT, Bb * NH), 256, 0, stream>>>(Opart, lpart, yb);
  k_gemm_proj128<<<dim3(Mp / 128, C_ / 128), 256, 0, stream>>>(yb, wpt, out);
}

// Round 14
// 204.027 us; speedup vs baseline: 1.0305x; 1.0305x over previous
//
#include <hip/hip_runtime.h>
#include <hip/hip_bf16.h>

typedef __attribute__((ext_vector_type(8))) short short8;
typedef __attribute__((ext_vector_type(4))) float f32x4;

#define MFMA16(a,b,c) __builtin_amdgcn_mfma_f32_16x16x32_bf16((a),(b),(c),0,0,0)

// Counted waits + raw barrier. NEVER drain vmcnt(0) mid-loop (T4).
#define WAITVM(N) asm volatile("s_waitcnt vmcnt(" #N ")" ::: "memory")
#define BAR()     asm volatile("s_barrier" ::: "memory")

constexpr int Tt = 1705;          // (L+1) + L*16 + L*196
constexpr int Tp = 1792;          // padded to 28*64
constexpr int NKT_ALL = 28;       // Tp/64 key tiles
constexpr int NH = 12, HD = 64, Bb = 4, C_ = 768;
constexpr int M_  = Bb * Tt;      // 6820
constexpr int Mp  = 6912;         // 27*256 = 54*128
constexpr int NQT = 14;           // 128-row q-tiles
constexpr int NCH = 4;            // key-range chunks per q-tile (split-K flash)
constexpr float QSCALE = 0.18033688011116016f;   // (1/8) * log2(e)

static_assert(Mp % 256 == 0 && (3 * C_) % 256 == 0, "256-tile grid");

__device__ __forceinline__ void gl16(const void* g, void* l) {
  __builtin_amdgcn_global_load_lds((const __attribute__((address_space(1))) void*)g,
                                   (__attribute__((address_space(3))) void*)l, 16, 0, 0);
}

// raw v_exp_f32 (no libm fixup). Inputs bounded; -1e30 -> 0.
__device__ __forceinline__ float ex2(float x) {
  float r; asm("v_exp_f32 %0, %1" : "=v"(r) : "v"(x)); return r;
}

// frame id of token t (t<1705). Action tokens (t<9) return their index.
__device__ __forceinline__ int frame_of(int t) {
  return t < 9 ? t : (t < 137 ? ((t - 9) >> 4) : ((t - 137) / 196));
}

// key-limit for a 16-row span starting at a (rows [a, a+15])
__device__ __forceinline__ int lim16(int a) {
  if (a >= Tt) return 0;
  int bnd = min(a + 15, Tt - 1);
  int fmax = (a == 0) ? 8 : frame_of(min(bnd, a < 137 ? 136 : bnd));
  return (fmax >= 8) ? Tt : 137 + (fmax + 1) * 196;
}

// ---------------- fused prep: conv x->bf16 + both W transposes ---------------
constexpr int PREP_CONV = Mp * C_ / 4 / 256;              // 5184 blocks
constexpr int PREP_TA   = (C_ / 32) * (3 * C_ / 32);      // 1728 blocks
constexpr int PREP_TB   = (C_ / 32) * (C_ / 32);          // 576 blocks

__global__ __launch_bounds__(256) void k_prep(const float* __restrict__ x,
                                              __hip_bfloat16* __restrict__ xb,
                                              const float* __restrict__ Wa,
                                              __hip_bfloat16* __restrict__ wat,
                                              const float* __restrict__ Wp,
                                              __hip_bfloat16* __restrict__ wpt) {
  __shared__ float tile[32][33];
  const int bid = blockIdx.x, tid = threadIdx.x;
  if (bid < PREP_CONV) {                        // ---- x fp32 -> bf16 (padded)
    int i = bid * 256 + tid;
    float4 v = make_float4(0.f, 0.f, 0.f, 0.f);
    if (i * 4 < M_ * C_) v = ((const float4*)x)[i];
    __hip_bfloat16 o0 = __float2bfloat16(v.x), o1 = __float2bfloat16(v.y),
                   o2 = __float2bfloat16(v.z), o3 = __float2bfloat16(v.w);
    ushort4 u = make_ushort4(*(unsigned short*)&o0, *(unsigned short*)&o1,
                             *(unsigned short*)&o2, *(unsigned short*)&o3);
    ((ushort4*)xb)[i] = u;
    return;
  }
  const float* src; __hip_bfloat16* dst; int N, bid2;
  if (bid < PREP_CONV + PREP_TA) { bid2 = bid - PREP_CONV; src = Wa; dst = wat; N = 3 * C_; }
  else                           { bid2 = bid - PREP_CONV - PREP_TA; src = Wp; dst = wpt; N = C_; }
  const int K = C_;
  int kb = (bid2 % (C_ / 32)) * 32, nb = (bid2 / (C_ / 32)) * 32;
  int tx = tid & 31, ty = tid >> 5;
  for (int i = 0; i < 4; i++)
    tile[ty + i * 8][tx] = src[(size_t)(kb + ty + i * 8) * N + nb + tx];
  __syncthreads();
  for (int i = 0; i < 4; i++)
    dst[(size_t)(nb + ty + i * 8) * K + kb + tx] = __float2bfloat16(tile[tx][ty + i * 8]);
}

// ---------------- 256x256-tile 8-wave qkv GEMM, 4-deep pipeline --------------
// R3 main loop + R9 LDS-staged coalesced epilogue. BEST-KNOWN (R10: 203.7 µs
// total). R11 (4-phase interleave) null; R13 (128² split) regressed — both
// tile shapes and all schedule variants measured; this config stands.
__global__ __launch_bounds__(512) void k_gemm_qkv(const __hip_bfloat16* __restrict__ xb,
                                                  const __hip_bfloat16* __restrict__ wat,
                                                  __hip_bfloat16* __restrict__ q,
                                                  __hip_bfloat16* __restrict__ kpk,
                                                  __hip_bfloat16* __restrict__ vpk) {
  __shared__ __hip_bfloat16 smem[65536];       // 128 KB: stage bufs / epi tile
  const int tid = threadIdx.x;                 // 0..511, 8 waves
  const int lane = tid & 63, w = tid >> 6;
  const int wr = w >> 2, wc = w & 3;           // wave -> (row-half, col-quarter)
  const int l16 = lane & 15, grp = lane >> 4;
  const int m0 = blockIdx.x * 256, n0 = blockIdx.y * 256;
  constexpr int NT = C_ / 32;                  // 24 K-tiles
  constexpr int ES = 132;                      // epi LDS row stride (elems)

  // stage K-tile t into buffer slot bb (4 gl16 per thread)
  auto stage = [&](int t, int bb) {
    int k0 = t * 32;
    __hip_bfloat16* As = smem + bb * 8192;
    __hip_bfloat16* Bs = smem + 32768 + bb * 8192;
    for (int p = 0; p < 2; p++) {
      int idx = p * 512 + tid;                 // [0,1024): row*4 + phys-chunk
      int row = idx >> 2;
      int c8 = (idx & 3) ^ ((row >> 1) & 3);   // proven swizzle (0 conflicts)
      gl16(xb  + (size_t)(m0 + row) * C_ + k0 + c8 * 8, As + idx * 8);
      gl16(wat + (size_t)(n0 + row) * C_ + k0 + c8 * 8, Bs + idx * 8);
    }
  };

  f32x4 acc[8][4];
  for (int i = 0; i < 8; i++)
    for (int j = 0; j < 4; j++) { f32x4 z = {0.f,0.f,0.f,0.f}; acc[i][j] = z; }

  stage(0, 0); stage(1, 1); stage(2, 2);

  for (int t = 0; t < NT; t++) {
    if (t + 3 < NT) stage(t + 3, (t + 3) & 3);
    int rem = NT - 1 - t;                      // tiles staged beyond t
    if (rem >= 3)      WAITVM(12);
    else if (rem == 2) WAITVM(8);
    else if (rem == 1) WAITVM(4);
    else               WAITVM(0);
    BAR();                                     // tile t visible to all waves
    const __hip_bfloat16* Ac = smem + (t & 3) * 8192;
    const __hip_bfloat16* Bc = smem + 32768 + (t & 3) * 8192;
    short8 bfr[4], afr[4];
    for (int nj = 0; nj < 4; nj++) {
      int row = wc * 64 + nj * 16 + l16;
      bfr[nj] = *(const short8*)(Bc + row * 32 + ((grp ^ ((row >> 1) & 3)) * 8));
    }
    for (int mi = 0; mi < 4; mi++) {
      int row = wr * 128 + mi * 16 + l16;
      afr[mi] = *(const short8*)(Ac + row * 32 + ((grp ^ ((row >> 1) & 3)) * 8));
    }
    __builtin_amdgcn_s_setprio(1);
    for (int mi = 0; mi < 4; mi++)
      for (int nj = 0; nj < 4; nj++)
        acc[mi][nj] = MFMA16(afr[mi], bfr[nj], acc[mi][nj]);
    __builtin_amdgcn_s_setprio(0);
    for (int mi = 0; mi < 4; mi++) {           // second row-half, B reused
      int row = wr * 128 + 64 + mi * 16 + l16;
      afr[mi] = *(const short8*)(Ac + row * 32 + ((grp ^ ((row >> 1) & 3)) * 8));
    }
    __builtin_amdgcn_s_setprio(1);
    for (int mi = 0; mi < 4; mi++)
      for (int nj = 0; nj < 4; nj++)
        acc[4 + mi][nj] = MFMA16(afr[mi], bfr[nj], acc[4 + mi][nj]);
    __builtin_amdgcn_s_setprio(0);
    BAR();                                     // readers of buf[t&3] done
  }

  // ---------------- R9 coalesced epilogue ----------------
  const int which = n0 / C_;                   // 0=q, 1=k, 2=v (block-uniform)
  const int cbase = n0 - which * C_;           // 0/256/512
  const int h0 = cbase >> 6;                   // first of 4 heads covered
  const float scale = (which == 0) ? QSCALE : 1.0f;
  const int b0 = m0 / Tt;
  const int b1 = min((m0 + 255) / Tt, Bb - 1);
  __hip_bfloat16* epi = smem;                  // [256][ES] tile (66 KB)

  // destination-order decode constants (verified fwd/bwd)
  const int mmD = tid & 15, ggD = (tid >> 4) & 3;
  const int loD = (tid >> 6) & 1, hiD = tid >> 7;
  const int tinK = hiD * 16 + mmD, dK = loD * 32 + ggD * 8;      // K: 8 consecutive d
  const int dV = hiD * 16 + mmD;                                  // V: 8 tokens, d fixed

  for (int pc = 0; pc < 2; pc++) {             // column half (2 heads each)
    // phase A: 4 waves (wc>>1 == pc) dump acc into epi
    if ((wc >> 1) == pc) {
      int colw = (wc & 1) * 64;
      for (int mi = 0; mi < 8; mi++)
        for (int nj = 0; nj < 4; nj++) {
          int row = wr * 128 + mi * 16 + grp * 4;
          int col = colw + nj * 16 + l16;
          #pragma unroll
          for (int r = 0; r < 4; r++)
            epi[(row + r) * ES + col] = __float2bfloat16(acc[mi][nj][r] * scale);
        }
    }
    __syncthreads();
    // phase B: destination-ordered coalesced writes
    for (int b = b0; b <= b1; b++) {
      int ts = max(0, m0 - b * Tt), te = min(Tt, m0 + 256 - b * Tt);
      if (ts >= te) continue;
      const int rb = b * Tt - m0;              // row = rb + t
      if (which == 0) {
        for (int hh = 0; hh < 2; hh++) {
          int bh = b * NH + h0 + pc * 2 + hh;
          __hip_bfloat16* qd = q + (size_t)bh * Tp * HD;
          for (int tc = ts & ~63; tc < te; tc += 64) {
            int t = tc + (tid >> 3);
            int d0 = (tid & 7) * 8;
            if (t >= ts && t < te) {
              int ad = (rb + t) * ES + hh * 64 + d0;
              union { short8 v; ushort4 h[2]; } u;
              u.h[0] = *(const ushort4*)(epi + ad);
              u.h[1] = *(const ushort4*)(epi + ad + 4);
              *(short8*)(qd + (size_t)t * HD + d0) = u.v;
            }
          }
        }
      } else if (which == 1) {
        for (int kt = ts >> 6; kt <= (te - 1) >> 6; kt++)
          for (int hh = 0; hh < 2; hh++) {
            int bh = b * NH + h0 + pc * 2 + hh;
            int t = kt * 64 + tinK;
            if (t >= ts && t < te) {
              int ad = (rb + t) * ES + hh * 64 + dK;
              union { short8 v; ushort4 h[2]; } u;
              u.h[0] = *(const ushort4*)(epi + ad);
              u.h[1] = *(const ushort4*)(epi + ad + 4);
              ((short8*)(kpk + ((size_t)bh * NKT_ALL + kt) * 4096))[tid] = u.v;
            }
          }
      } else {
        for (int kt = ts >> 6; kt <= (te - 1) >> 6; kt++)
          for (int hh = 0; hh < 2; hh++) {
            int bh = b * NH + h0 + pc * 2 + hh;
            __hip_bfloat16* vd = vpk + ((size_t)bh * NKT_ALL + kt) * 4096;
            bool full = (kt * 64 >= ts) && (kt * 64 + 64 <= te);
            if (full) {
              short8 v;
              #pragma unroll
              for (int s = 0; s < 8; s++) {
                int tin = loD * 32 + ggD * 4 + (s & 3) + ((s >> 2) << 4);
                v[s] = *(const short*)(epi + (rb + kt * 64 + tin) * ES + hh * 64 + dV);
              }
              ((short8*)vd)[tid] = v;
            } else {
              #pragma unroll
              for (int s = 0; s < 8; s++) {
                int tin = loD * 32 + ggD * 4 + (s & 3) + ((s >> 2) << 4);
                int t = kt * 64 + tin;
                if (t >= ts && t < te)
                  vd[tid * 8 + s] = epi[(rb + t) * ES + hh * 64 + dV];
              }
            }
          }
      }
    }
    __syncthreads();                           // epi reads done before next pc
  }
}

// ---------------- 128x128-tile proj GEMM, 4-deep pipeline --------------------
// R10 form. FROZEN.
__global__ __launch_bounds__(256) void k_gemm_proj128(const __hip_bfloat16* __restrict__ A,
                                                      const __hip_bfloat16* __restrict__ Bt,
                                                      float* __restrict__ out) {
  __shared__ __hip_bfloat16 As[4][128 * 32], Bs[4][128 * 32];   // 64 KB
  const int tid = threadIdx.x;                 // 0..255, 4 waves
  const int lane = tid & 63, w = tid >> 6;
  const int wr = w >> 1, wc = w & 1;           // wave -> (row-half, col-half)
  const int l16 = lane & 15, grp = lane >> 4;
  const int m0 = blockIdx.x * 128, n0 = blockIdx.y * 128;
  constexpr int NT = C_ / 32;                  // 24 K-tiles

  auto stage = [&](int t, int bb) {
    int k0 = t * 32;
    for (int p = 0; p < 2; p++) {
      int idx = p * 256 + tid;                 // [0,512): row*4 + phys-chunk
      int row = idx >> 2;
      int c8 = (idx & 3) ^ ((row >> 1) & 3);   // proven swizzle (0 conflicts)
      gl16(A  + (size_t)(m0 + row) * C_ + k0 + c8 * 8, &As[bb][idx * 8]);
      gl16(Bt + (size_t)(n0 + row) * C_ + k0 + c8 * 8, &Bs[bb][idx * 8]);
    }
  };

  f32x4 acc[4][4];
  for (int i = 0; i < 4; i++)
    for (int j = 0; j < 4; j++) { f32x4 z = {0.f,0.f,0.f,0.f}; acc[i][j] = z; }

  stage(0, 0); stage(1, 1); stage(2, 2);

  for (int t = 0; t < NT; t++) {
    if (t + 3 < NT) stage(t + 3, (t + 3) & 3);
    int rem = NT - 1 - t;
    if (rem >= 3)      WAITVM(12);
    else if (rem == 2) WAITVM(8);
    else if (rem == 1) WAITVM(4);
    else               WAITVM(0);
    BAR();
    const __hip_bfloat16* Ac = As[t & 3];
    const __hip_bfloat16* Bc = Bs[t & 3];
    short8 afr[4], bfr[4];
    for (int nj = 0; nj < 4; nj++) {
      int row = wc * 64 + nj * 16 + l16;
      bfr[nj] = *(const short8*)(Bc + row * 32 + ((grp ^ ((row >> 1) & 3)) * 8));
    }
    for (int mi = 0; mi < 4; mi++) {
      int row = wr * 64 + mi * 16 + l16;
      afr[mi] = *(const short8*)(Ac + row * 32 + ((grp ^ ((row >> 1) & 3)) * 8));
    }
    __builtin_amdgcn_s_setprio(1);
    for (int mi = 0; mi < 4; mi++)
      for (int nj = 0; nj < 4; nj++)
        acc[mi][nj] = MFMA16(afr[mi], bfr[nj], acc[mi][nj]);
    __builtin_amdgcn_s_setprio(0);
    BAR();
  }

  for (int mi = 0; mi < 4; mi++)
    for (int r = 0; r < 4; r++) {
      int m = m0 + wr * 64 + mi * 16 + grp * 4 + r;
      if (m >= M_) continue;
      for (int nj = 0; nj < 4; nj++)
        out[(size_t)m * C_ + n0 + wc * 64 + nj * 16 + l16] = acc[mi][nj][r];
    }
}

// ---------------- barrier-free, LDS-free split-K flash attention -------------
// FROZEN (R3 body + QLUT). R4-R7 proved every pipelining/remap/occupancy
// variant regresses; attn lives on TLP at VGPR 84, plateau ~55 µs.
union S8u { short8 v; struct { unsigned long long lo, hi; } q; unsigned u[4]; };

__device__ __forceinline__ unsigned pack2bf(float a, float b) {
  union { __hip_bfloat162 h; unsigned u; } cv;
  cv.h = __float22bfloat162_rn(make_float2(a, b));
  return cv.u;
}

__constant__ int QLUT[NQT] = {0, 1, 11, 12, 13, 10, 8, 9, 7, 5, 6, 4, 2, 3};

__global__ __launch_bounds__(256, 2) void k_attn(const __hip_bfloat16* __restrict__ q,
                                                 const __hip_bfloat16* __restrict__ kpk,
                                                 const __hip_bfloat16* __restrict__ vpk,
                                                 __hip_bfloat16* __restrict__ Opart,
                                                 float* __restrict__ lpart) {
  const int tid = threadIdx.x, lane = tid & 63, w = tid >> 6;
  const int l16 = lane & 15, grp = lane >> 4;
  // XCD-aware decode: id = (bh&7) + 8*(cq + 56*(bh>>3)); longest-first qt
  const int id = blockIdx.x;
  const int xslot = id & 7, rr_ = id >> 3;
  const int bh = xslot + 8 * (rr_ / 56);
  const int cqs = rr_ % 56;                     // qslot*NCH + ch
  const int qt = QLUT[cqs >> 2], ch = cqs & (NCH - 1);
  const int cq = qt * NCH + ch;                 // actual output block index
  const int t0q = qt * 128;
  const __hip_bfloat16* qb = q + (size_t)bh * Tp * HD;

  int lim[2], Cmn[2], Ath[2], Bth[2], Cth[2];
  for (int g = 0; g < 2; g++) {
    int a = t0q + w * 32 + g * 16;
    lim[g] = lim16(a);
    int fqmn, fql;
    if (a >= Tt) { fqmn = 8; fql = 8; }
    else {
      int bnd = min(a + 15, Tt - 1);
      fqmn = min(frame_of(a), frame_of(bnd));
      int t = a + l16;
      fql = (t >= Tt) ? 8 : frame_of(t);
    }
    Cmn[g] = min(137 + 196 * (fqmn + 1), Tt);   // wave-wide full-tile bound
    Ath[g] = fql + 2;                            // action keys: key < A
    Bth[g] = 9 + 16 * (fql + 1);                 // tactile keys: key < B
    Cth[g] = min(137 + 196 * (fql + 1), Tt);     // image keys: key < C
  }
  int limw = max(lim[0], lim[1]);
  int nktw = (limw + 63) >> 6;                  // this wave's needed tiles
  int k0t = (ch * nktw) >> 2;                   // balanced split
  int k1t = ((ch + 1) * nktw) >> 2;

  // Q fragments (once per wave)
  short8 qa[2][2];
  for (int g = 0; g < 2; g++) {
    const __hip_bfloat16* qr = qb + (size_t)(t0q + w * 32 + g * 16 + l16) * HD + grp * 8;
    qa[g][0] = *(const short8*)(qr);
    qa[g][1] = *(const short8*)(qr + 32);
  }
  f32x4 o[2][4];
  for (int g = 0; g < 2; g++)
    for (int jt = 0; jt < 4; jt++) { f32x4 z = {0.f,0.f,0.f,0.f}; o[g][jt] = z; }
  f32x4 ps[2];
  { f32x4 z = {0.f,0.f,0.f,0.f}; ps[0] = z; ps[1] = z; }

  const short8* kbase = (const short8*)(kpk + (size_t)bh * NKT_ALL * 4096);
  const short8* vbase = (const short8*)(vpk + (size_t)bh * NKT_ALL * 4096);

  for (int kt = k0t; kt < k1t; kt++) {
    const int t0k = kt * 64;
    const short8* kp = kbase + (size_t)kt * 512;
    const short8* vp = vbase + (size_t)kt * 512;
    short8 kf[4][2], vf[4][2];
    for (int j = 0; j < 4; j++)
      for (int hh = 0; hh < 2; hh++) kf[j][hh] = kp[(j * 2 + hh) * 64 + lane];
    for (int jt = 0; jt < 4; jt++)
      for (int kb2 = 0; kb2 < 2; kb2++) vf[jt][kb2] = vp[(jt * 2 + kb2) * 64 + lane];

    f32x4 s[2][4];
    for (int j = 0; j < 4; j++) {               // S^T = K * Q^T
      f32x4 z = {0.f,0.f,0.f,0.f};
      s[0][j] = MFMA16(kf[j][0], qa[0][0], z);
      s[0][j] = MFMA16(kf[j][1], qa[0][1], s[0][j]);
      s[1][j] = MFMA16(kf[j][0], qa[1][0], z);
      s[1][j] = MFMA16(kf[j][1], qa[1][1], s[1][j]);
    }

    bool act0 = t0k < lim[0], act1 = t0k < lim[1];
    bool fullk = (t0k + 64 <= Tt);
    S8u pf[2][2];
    for (int g = 0; g < 2; g++) {
      bool act = g == 0 ? act0 : act1;
      if (!act) continue;                       // wave-uniform
      bool needm = !(fullk && (t0k >= 192 ? (t0k + 64) <= Cmn[g] : Cmn[g] >= Tt));
      if (needm) {                              // threshold-compare mask
        for (int j = 0; j < 4; j++)
          for (int r = 0; r < 4; r++) {
            int key = t0k + j * 16 + grp * 4 + r;
            int thr = key < 9 ? Ath[g] : (key < 137 ? Bth[g] : Cth[g]);
            if (key >= thr) s[g][j][r] = -1e30f;
          }
      }
      f32x4 p[4];
      for (int j = 0; j < 4; j++)
        for (int r = 0; r < 4; r++) p[j][r] = ex2(s[g][j][r]);
      ps[g] += (p[0] + p[1]) + (p[2] + p[3]);   // deferred reduction
      pf[g][0].u[0] = pack2bf(p[0][0], p[0][1]);
      pf[g][0].u[1] = pack2bf(p[0][2], p[0][3]);
      pf[g][0].u[2] = pack2bf(p[1][0], p[1][1]);
      pf[g][0].u[3] = pack2bf(p[1][2], p[1][3]);
      pf[g][1].u[0] = pack2bf(p[2][0], p[2][1]);
      pf[g][1].u[1] = pack2bf(p[2][2], p[2][3]);
      pf[g][1].u[2] = pack2bf(p[3][0], p[3][1]);
      pf[g][1].u[3] = pack2bf(p[3][2], p[3][3]);
    }

    for (int jt = 0; jt < 4; jt++)              // O^T += V^T * P^T
      for (int kb2 = 0; kb2 < 2; kb2++) {
        if (act0) o[0][jt] = MFMA16(vf[jt][kb2], pf[0][kb2].v, o[0][jt]);
        if (act1) o[1][jt] = MFMA16(vf[jt][kb2], pf[1][kb2].v, o[1][jt]);
      }
  }

  // final softmax-denominator reduction (once, not per tile)
  float lr[2];
  for (int g = 0; g < 2; g++) {
    float sum = (ps[g][0] + ps[g][1]) + (ps[g][2] + ps[g][3]);
    sum += __shfl_xor(sum, 16);
    sum += __shfl_xor(sum, 32);
    lr[g] = sum;
  }

  // epilogue: unnormalized bf16 partials (always written, zeros if empty)
  const int blk = bh * (NQT * NCH) + cq;
  __hip_bfloat16* op = Opart + (size_t)blk * (128 * 64);
  for (int g = 0; g < 2; g++) {
    int row = w * 32 + g * 16 + l16;
    for (int jt = 0; jt < 4; jt++) {
      unsigned p01 = pack2bf(o[g][jt][0], o[g][jt][1]);
      unsigned p23 = pack2bf(o[g][jt][2], o[g][jt][3]);
      ushort4 u;
      u.x = p01 & 0xffff; u.y = p01 >> 16; u.z = p23 & 0xffff; u.w = p23 >> 16;
      *(ushort4*)(op + row * 64 + jt * 16 + grp * 4) = u;
    }
    if (grp == 0) lpart[(size_t)blk * 128 + w * 32 + g * 16 + l16] = lr[g];
  }
}

// sum NCH chunk partials, normalize, write y bf16
__global__ __launch_bounds__(256) void k_combine(const __hip_bfloat16* __restrict__ Opart,
                                                 const float* __restrict__ lpart,
                                                 __hip_bfloat16* __restrict__ y) {
  const int tid = threadIdx.x;
  const int qt = blockIdx.x, bh = blockIdx.y;
  const int b = bh / NH, h = bh - b * NH;
  const int t0q = qt * 128;
  const int blk0 = bh * (NQT * NCH) + qt * NCH;
  __shared__ float ls[128];
  if (tid < 128) {
    float s = 0.f;
    for (int c = 0; c < NCH; c++) s += lpart[(size_t)(blk0 + c) * 128 + tid];
    ls[tid] = (s > 0.f) ? 1.0f / s : 0.f;
  }
  __syncthreads();
  for (int it = 0; it < 4; it++) {
    int e8 = it * 256 + tid;                     // 8-elem group in [0,1024)
    int e = e8 * 8;
    int row = e >> 6, d = e & 63;
    int t = t0q + row;
    if (t >= Tt) continue;
    float acc[8] = {0,0,0,0,0,0,0,0};
    for (int c = 0; c < NCH; c++) {
      short8 vv = *(const short8*)(Opart + (size_t)(blk0 + c) * (128 * 64) + e);
      for (int i = 0; i < 8; i++) {
        union { unsigned u; float f; } cv;
        cv.u = ((unsigned)(unsigned short)vv[i]) << 16;
        acc[i] += cv.f;
      }
    }
    float rinv = ls[row];
    short8 outv;
    for (int i = 0; i < 8; i += 2) {
      unsigned p = pack2bf(acc[i] * rinv, acc[i + 1] * rinv);
      outv[i] = (short)(p & 0xffff);
      outv[i + 1] = (short)(p >> 16);
    }
    *(short8*)(y + (size_t)(b * Tt + t) * C_ + h * 64 + d) = outv;
  }
}

extern "C" void kernel_launch(void* const* d_in, const int* in_sizes, int n_in,
                              void* d_out, int out_size, void* d_ws, size_t ws_size,
                              hipStream_t stream) {
  const float* x  = (const float*)d_in[0];
  const float* Wa = (const float*)d_in[1];
  const float* Wp = (const float*)d_in[2];
  float* out = (float*)d_out;

  char* ws = (char*)d_ws;
  size_t off = 0;
  auto alloc = [&](size_t bytes) { size_t r = off; off += (bytes + 255) & ~(size_t)255; return r; };
  __hip_bfloat16* xb  = (__hip_bfloat16*)(ws + alloc((size_t)Mp * C_ * 2));
  __hip_bfloat16* wat = (__hip_bfloat16*)(ws + alloc((size_t)3 * C_ * C_ * 2));
  __hip_bfloat16* wpt = (__hip_bfloat16*)(ws + alloc((size_t)C_ * C_ * 2));
  __hip_bfloat16* qb  = (__hip_bfloat16*)(ws + alloc((size_t)Bb * NH * Tp * HD * 2));
  __hip_bfloat16* kpk = (__hip_bfloat16*)(ws + alloc((size_t)Bb * NH * NKT_ALL * 4096 * 2));
  __hip_bfloat16* vpk = (__hip_bfloat16*)(ws + alloc((size_t)Bb * NH * NKT_ALL * 4096 * 2));
  __hip_bfloat16* yb  = (__hip_bfloat16*)(ws + alloc((size_t)Mp * C_ * 2));
  __hip_bfloat16* Opart = (__hip_bfloat16*)(ws + alloc((size_t)Bb * NH * NQT * NCH * 128 * 64 * 2));
  float*          lpart = (float*)(ws + alloc((size_t)Bb * NH * NQT * NCH * 128 * 4));

  k_prep<<<PREP_CONV + PREP_TA + PREP_TB, 256, 0, stream>>>(x, xb, Wa, wat, Wp, wpt);
  k_gemm_qkv<<<dim3(Mp / 256, 3 * C_ / 256), 512, 0, stream>>>(xb, wat, qb, kpk, vpk);
  k_attn<<<dim3(Bb * NH * NQT * NCH), 256, 0, stream>>>(qb, kpk, vpk, Opart, lpart);
  k_combine<<<dim3(NQT, Bb * NH), 256, 0, stream>>>(Opart, lpart, yb);
  k_gemm_proj128<<<dim3(Mp / 128, C_ / 128), 256, 0, stream>>>(yb, wpt, out);
}

// Round 15
// 201.498 us; speedup vs baseline: 1.0434x; 1.0126x over previous
//
#include <hip/hip_runtime.h>
#include <hip/hip_bf16.h>

typedef __attribute__((ext_vector_type(8))) short short8;
typedef __attribute__((ext_vector_type(4))) float f32x4;

#define MFMA16(a,b,c) __builtin_amdgcn_mfma_f32_16x16x32_bf16((a),(b),(c),0,0,0)

// Counted waits + raw barrier. NEVER drain vmcnt(0) mid-loop (T4).
#define WAITVM(N) asm volatile("s_waitcnt vmcnt(" #N ")" ::: "memory")
#define BAR()     asm volatile("s_barrier" ::: "memory")

constexpr int Tt = 1705;          // (L+1) + L*16 + L*196
constexpr int Tp = 1792;          // padded to 28*64
constexpr int NKT_ALL = 28;       // Tp/64 key tiles
constexpr int NH = 12, HD = 64, Bb = 4, C_ = 768;
constexpr int M_  = Bb * Tt;      // 6820
constexpr int Mp  = 6912;         // 27*256 = 54*128
constexpr int NQT = 14;           // 128-row q-tiles
constexpr int NCH = 2;            // R15: key-range chunks (R5 pre-commit,
                                  // isolated at last: halves Opart traffic)
constexpr float QSCALE = 0.18033688011116016f;   // (1/8) * log2(e)

static_assert(Mp % 256 == 0 && (3 * C_) % 256 == 0, "256-tile grid");

__device__ __forceinline__ void gl16(const void* g, void* l) {
  __builtin_amdgcn_global_load_lds((const __attribute__((address_space(1))) void*)g,
                                   (__attribute__((address_space(3))) void*)l, 16, 0, 0);
}

// raw v_exp_f32 (no libm fixup). Inputs bounded; -1e30 -> 0.
__device__ __forceinline__ float ex2(float x) {
  float r; asm("v_exp_f32 %0, %1" : "=v"(r) : "v"(x)); return r;
}

// frame id of token t (t<1705). Action tokens (t<9) return their index.
__device__ __forceinline__ int frame_of(int t) {
  return t < 9 ? t : (t < 137 ? ((t - 9) >> 4) : ((t - 137) / 196));
}

// key-limit for a 16-row span starting at a (rows [a, a+15])
__device__ __forceinline__ int lim16(int a) {
  if (a >= Tt) return 0;
  int bnd = min(a + 15, Tt - 1);
  int fmax = (a == 0) ? 8 : frame_of(min(bnd, a < 137 ? 136 : bnd));
  return (fmax >= 8) ? Tt : 137 + (fmax + 1) * 196;
}

// ---------------- fused prep: conv x->bf16 + both W transposes ---------------
constexpr int PREP_CONV = Mp * C_ / 4 / 256;              // 5184 blocks
constexpr int PREP_TA   = (C_ / 32) * (3 * C_ / 32);      // 1728 blocks
constexpr int PREP_TB   = (C_ / 32) * (C_ / 32);          // 576 blocks

__global__ __launch_bounds__(256) void k_prep(const float* __restrict__ x,
                                              __hip_bfloat16* __restrict__ xb,
                                              const float* __restrict__ Wa,
                                              __hip_bfloat16* __restrict__ wat,
                                              const float* __restrict__ Wp,
                                              __hip_bfloat16* __restrict__ wpt) {
  __shared__ float tile[32][33];
  const int bid = blockIdx.x, tid = threadIdx.x;
  if (bid < PREP_CONV) {                        // ---- x fp32 -> bf16 (padded)
    int i = bid * 256 + tid;
    float4 v = make_float4(0.f, 0.f, 0.f, 0.f);
    if (i * 4 < M_ * C_) v = ((const float4*)x)[i];
    __hip_bfloat16 o0 = __float2bfloat16(v.x), o1 = __float2bfloat16(v.y),
                   o2 = __float2bfloat16(v.z), o3 = __float2bfloat16(v.w);
    ushort4 u = make_ushort4(*(unsigned short*)&o0, *(unsigned short*)&o1,
                             *(unsigned short*)&o2, *(unsigned short*)&o3);
    ((ushort4*)xb)[i] = u;
    return;
  }
  const float* src; __hip_bfloat16* dst; int N, bid2;
  if (bid < PREP_CONV + PREP_TA) { bid2 = bid - PREP_CONV; src = Wa; dst = wat; N = 3 * C_; }
  else                           { bid2 = bid - PREP_CONV - PREP_TA; src = Wp; dst = wpt; N = C_; }
  const int K = C_;
  int kb = (bid2 % (C_ / 32)) * 32, nb = (bid2 / (C_ / 32)) * 32;
  int tx = tid & 31, ty = tid >> 5;
  for (int i = 0; i < 4; i++)
    tile[ty + i * 8][tx] = src[(size_t)(kb + ty + i * 8) * N + nb + tx];
  __syncthreads();
  for (int i = 0; i < 4; i++)
    dst[(size_t)(nb + ty + i * 8) * K + kb + tx] = __float2bfloat16(tile[tx][ty + i * 8]);
}

// ---------------- 256x256-tile 8-wave qkv GEMM, 4-deep pipeline --------------
// R3 main loop + R9 LDS-staged coalesced epilogue. BEST-KNOWN. FROZEN.
__global__ __launch_bounds__(512) void k_gemm_qkv(const __hip_bfloat16* __restrict__ xb,
                                                  const __hip_bfloat16* __restrict__ wat,
                                                  __hip_bfloat16* __restrict__ q,
                                                  __hip_bfloat16* __restrict__ kpk,
                                                  __hip_bfloat16* __restrict__ vpk) {
  __shared__ __hip_bfloat16 smem[65536];       // 128 KB: stage bufs / epi tile
  const int tid = threadIdx.x;                 // 0..511, 8 waves
  const int lane = tid & 63, w = tid >> 6;
  const int wr = w >> 2, wc = w & 3;           // wave -> (row-half, col-quarter)
  const int l16 = lane & 15, grp = lane >> 4;
  const int m0 = blockIdx.x * 256, n0 = blockIdx.y * 256;
  constexpr int NT = C_ / 32;                  // 24 K-tiles
  constexpr int ES = 132;                      // epi LDS row stride (elems)

  // stage K-tile t into buffer slot bb (4 gl16 per thread)
  auto stage = [&](int t, int bb) {
    int k0 = t * 32;
    __hip_bfloat16* As = smem + bb * 8192;
    __hip_bfloat16* Bs = smem + 32768 + bb * 8192;
    for (int p = 0; p < 2; p++) {
      int idx = p * 512 + tid;                 // [0,1024): row*4 + phys-chunk
      int row = idx >> 2;
      int c8 = (idx & 3) ^ ((row >> 1) & 3);   // proven swizzle (0 conflicts)
      gl16(xb  + (size_t)(m0 + row) * C_ + k0 + c8 * 8, As + idx * 8);
      gl16(wat + (size_t)(n0 + row) * C_ + k0 + c8 * 8, Bs + idx * 8);
    }
  };

  f32x4 acc[8][4];
  for (int i = 0; i < 8; i++)
    for (int j = 0; j < 4; j++) { f32x4 z = {0.f,0.f,0.f,0.f}; acc[i][j] = z; }

  stage(0, 0); stage(1, 1); stage(2, 2);

  for (int t = 0; t < NT; t++) {
    if (t + 3 < NT) stage(t + 3, (t + 3) & 3);
    int rem = NT - 1 - t;                      // tiles staged beyond t
    if (rem >= 3)      WAITVM(12);
    else if (rem == 2) WAITVM(8);
    else if (rem == 1) WAITVM(4);
    else               WAITVM(0);
    BAR();                                     // tile t visible to all waves
    const __hip_bfloat16* Ac = smem + (t & 3) * 8192;
    const __hip_bfloat16* Bc = smem + 32768 + (t & 3) * 8192;
    short8 bfr[4], afr[4];
    for (int nj = 0; nj < 4; nj++) {
      int row = wc * 64 + nj * 16 + l16;
      bfr[nj] = *(const short8*)(Bc + row * 32 + ((grp ^ ((row >> 1) & 3)) * 8));
    }
    for (int mi = 0; mi < 4; mi++) {
      int row = wr * 128 + mi * 16 + l16;
      afr[mi] = *(const short8*)(Ac + row * 32 + ((grp ^ ((row >> 1) & 3)) * 8));
    }
    __builtin_amdgcn_s_setprio(1);
    for (int mi = 0; mi < 4; mi++)
      for (int nj = 0; nj < 4; nj++)
        acc[mi][nj] = MFMA16(afr[mi], bfr[nj], acc[mi][nj]);
    __builtin_amdgcn_s_setprio(0);
    for (int mi = 0; mi < 4; mi++) {           // second row-half, B reused
      int row = wr * 128 + 64 + mi * 16 + l16;
      afr[mi] = *(const short8*)(Ac + row * 32 + ((grp ^ ((row >> 1) & 3)) * 8));
    }
    __builtin_amdgcn_s_setprio(1);
    for (int mi = 0; mi < 4; mi++)
      for (int nj = 0; nj < 4; nj++)
        acc[4 + mi][nj] = MFMA16(afr[mi], bfr[nj], acc[4 + mi][nj]);
    __builtin_amdgcn_s_setprio(0);
    BAR();                                     // readers of buf[t&3] done
  }

  // ---------------- R9 coalesced epilogue ----------------
  const int which = n0 / C_;                   // 0=q, 1=k, 2=v (block-uniform)
  const int cbase = n0 - which * C_;           // 0/256/512
  const int h0 = cbase >> 6;                   // first of 4 heads covered
  const float scale = (which == 0) ? QSCALE : 1.0f;
  const int b0 = m0 / Tt;
  const int b1 = min((m0 + 255) / Tt, Bb - 1);
  __hip_bfloat16* epi = smem;                  // [256][ES] tile (66 KB)

  // destination-order decode constants (verified fwd/bwd)
  const int mmD = tid & 15, ggD = (tid >> 4) & 3;
  const int loD = (tid >> 6) & 1, hiD = tid >> 7;
  const int tinK = hiD * 16 + mmD, dK = loD * 32 + ggD * 8;      // K: 8 consecutive d
  const int dV = hiD * 16 + mmD;                                  // V: 8 tokens, d fixed

  for (int pc = 0; pc < 2; pc++) {             // column half (2 heads each)
    // phase A: 4 waves (wc>>1 == pc) dump acc into epi
    if ((wc >> 1) == pc) {
      int colw = (wc & 1) * 64;
      for (int mi = 0; mi < 8; mi++)
        for (int nj = 0; nj < 4; nj++) {
          int row = wr * 128 + mi * 16 + grp * 4;
          int col = colw + nj * 16 + l16;
          #pragma unroll
          for (int r = 0; r < 4; r++)
            epi[(row + r) * ES + col] = __float2bfloat16(acc[mi][nj][r] * scale);
        }
    }
    __syncthreads();
    // phase B: destination-ordered coalesced writes
    for (int b = b0; b <= b1; b++) {
      int ts = max(0, m0 - b * Tt), te = min(Tt, m0 + 256 - b * Tt);
      if (ts >= te) continue;
      const int rb = b * Tt - m0;              // row = rb + t
      if (which == 0) {
        for (int hh = 0; hh < 2; hh++) {
          int bh = b * NH + h0 + pc * 2 + hh;
          __hip_bfloat16* qd = q + (size_t)bh * Tp * HD;
          for (int tc = ts & ~63; tc < te; tc += 64) {
            int t = tc + (tid >> 3);
            int d0 = (tid & 7) * 8;
            if (t >= ts && t < te) {
              int ad = (rb + t) * ES + hh * 64 + d0;
              union { short8 v; ushort4 h[2]; } u;
              u.h[0] = *(const ushort4*)(epi + ad);
              u.h[1] = *(const ushort4*)(epi + ad + 4);
              *(short8*)(qd + (size_t)t * HD + d0) = u.v;
            }
          }
        }
      } else if (which == 1) {
        for (int kt = ts >> 6; kt <= (te - 1) >> 6; kt++)
          for (int hh = 0; hh < 2; hh++) {
            int bh = b * NH + h0 + pc * 2 + hh;
            int t = kt * 64 + tinK;
            if (t >= ts && t < te) {
              int ad = (rb + t) * ES + hh * 64 + dK;
              union { short8 v; ushort4 h[2]; } u;
              u.h[0] = *(const ushort4*)(epi + ad);
              u.h[1] = *(const ushort4*)(epi + ad + 4);
              ((short8*)(kpk + ((size_t)bh * NKT_ALL + kt) * 4096))[tid] = u.v;
            }
          }
      } else {
        for (int kt = ts >> 6; kt <= (te - 1) >> 6; kt++)
          for (int hh = 0; hh < 2; hh++) {
            int bh = b * NH + h0 + pc * 2 + hh;
            __hip_bfloat16* vd = vpk + ((size_t)bh * NKT_ALL + kt) * 4096;
            bool full = (kt * 64 >= ts) && (kt * 64 + 64 <= te);
            if (full) {
              short8 v;
              #pragma unroll
              for (int s = 0; s < 8; s++) {
                int tin = loD * 32 + ggD * 4 + (s & 3) + ((s >> 2) << 4);
                v[s] = *(const short*)(epi + (rb + kt * 64 + tin) * ES + hh * 64 + dV);
              }
              ((short8*)vd)[tid] = v;
            } else {
              #pragma unroll
              for (int s = 0; s < 8; s++) {
                int tin = loD * 32 + ggD * 4 + (s & 3) + ((s >> 2) << 4);
                int t = kt * 64 + tin;
                if (t >= ts && t < te)
                  vd[tid * 8 + s] = epi[(rb + t) * ES + hh * 64 + dV];
              }
            }
          }
      }
    }
    __syncthreads();                           // epi reads done before next pc
  }
}

// ---------------- 128x128-tile proj GEMM, 4-deep pipeline --------------------
// R10 form. FROZEN.
__global__ __launch_bounds__(256) void k_gemm_proj128(const __hip_bfloat16* __restrict__ A,
                                                      const __hip_bfloat16* __restrict__ Bt,
                                                      float* __restrict__ out) {
  __shared__ __hip_bfloat16 As[4][128 * 32], Bs[4][128 * 32];   // 64 KB
  const int tid = threadIdx.x;                 // 0..255, 4 waves
  const int lane = tid & 63, w = tid >> 6;
  const int wr = w >> 1, wc = w & 1;           // wave -> (row-half, col-half)
  const int l16 = lane & 15, grp = lane >> 4;
  const int m0 = blockIdx.x * 128, n0 = blockIdx.y * 128;
  constexpr int NT = C_ / 32;                  // 24 K-tiles

  auto stage = [&](int t, int bb) {
    int k0 = t * 32;
    for (int p = 0; p < 2; p++) {
      int idx = p * 256 + tid;                 // [0,512): row*4 + phys-chunk
      int row = idx >> 2;
      int c8 = (idx & 3) ^ ((row >> 1) & 3);   // proven swizzle (0 conflicts)
      gl16(A  + (size_t)(m0 + row) * C_ + k0 + c8 * 8, &As[bb][idx * 8]);
      gl16(Bt + (size_t)(n0 + row) * C_ + k0 + c8 * 8, &Bs[bb][idx * 8]);
    }
  };

  f32x4 acc[4][4];
  for (int i = 0; i < 4; i++)
    for (int j = 0; j < 4; j++) { f32x4 z = {0.f,0.f,0.f,0.f}; acc[i][j] = z; }

  stage(0, 0); stage(1, 1); stage(2, 2);

  for (int t = 0; t < NT; t++) {
    if (t + 3 < NT) stage(t + 3, (t + 3) & 3);
    int rem = NT - 1 - t;
    if (rem >= 3)      WAITVM(12);
    else if (rem == 2) WAITVM(8);
    else if (rem == 1) WAITVM(4);
    else               WAITVM(0);
    BAR();
    const __hip_bfloat16* Ac = As[t & 3];
    const __hip_bfloat16* Bc = Bs[t & 3];
    short8 afr[4], bfr[4];
    for (int nj = 0; nj < 4; nj++) {
      int row = wc * 64 + nj * 16 + l16;
      bfr[nj] = *(const short8*)(Bc + row * 32 + ((grp ^ ((row >> 1) & 3)) * 8));
    }
    for (int mi = 0; mi < 4; mi++) {
      int row = wr * 64 + mi * 16 + l16;
      afr[mi] = *(const short8*)(Ac + row * 32 + ((grp ^ ((row >> 1) & 3)) * 8));
    }
    __builtin_amdgcn_s_setprio(1);
    for (int mi = 0; mi < 4; mi++)
      for (int nj = 0; nj < 4; nj++)
        acc[mi][nj] = MFMA16(afr[mi], bfr[nj], acc[mi][nj]);
    __builtin_amdgcn_s_setprio(0);
    BAR();
  }

  for (int mi = 0; mi < 4; mi++)
    for (int r = 0; r < 4; r++) {
      int m = m0 + wr * 64 + mi * 16 + grp * 4 + r;
      if (m >= M_) continue;
      for (int nj = 0; nj < 4; nj++)
        out[(size_t)m * C_ + n0 + wc * 64 + nj * 16 + l16] = acc[mi][nj][r];
    }
}

// ---------------- barrier-free, LDS-free split-K flash attention -------------
// R15: R3 body + QLUT, NCH 4->2 (the R5 pre-committed isolated ablation).
// Attn body/masks/epilogue formulas untouched; only the split decode and
// the chunk bounds change. Opart/lpart traffic halves (44.3 -> 22.2 MB).
union S8u { short8 v; struct { unsigned long long lo, hi; } q; unsigned u[4]; };

__device__ __forceinline__ unsigned pack2bf(float a, float b) {
  union { __hip_bfloat162 h; unsigned u; } cv;
  cv.h = __float22bfloat162_rn(make_float2(a, b));
  return cv.u;
}

__constant__ int QLUT[NQT] = {0, 1, 11, 12, 13, 10, 8, 9, 7, 5, 6, 4, 2, 3};

__global__ __launch_bounds__(256, 2) void k_attn(const __hip_bfloat16* __restrict__ q,
                                                 const __hip_bfloat16* __restrict__ kpk,
                                                 const __hip_bfloat16* __restrict__ vpk,
                                                 __hip_bfloat16* __restrict__ Opart,
                                                 float* __restrict__ lpart) {
  const int tid = threadIdx.x, lane = tid & 63, w = tid >> 6;
  const int l16 = lane & 15, grp = lane >> 4;
  // XCD-aware decode: id = (bh&7) + 8*(cqs + 28*(bh>>3)); longest-first qt
  const int id = blockIdx.x;
  const int xslot = id & 7, rr_ = id >> 3;
  const int bh = xslot + 8 * (rr_ / (NQT * NCH));
  const int cqs = rr_ % (NQT * NCH);            // qslot*NCH + ch
  const int qt = QLUT[cqs / NCH], ch = cqs % NCH;
  const int cq = qt * NCH + ch;                 // actual output block index
  const int t0q = qt * 128;
  const __hip_bfloat16* qb = q + (size_t)bh * Tp * HD;

  int lim[2], Cmn[2], Ath[2], Bth[2], Cth[2];
  for (int g = 0; g < 2; g++) {
    int a = t0q + w * 32 + g * 16;
    lim[g] = lim16(a);
    int fqmn, fql;
    if (a >= Tt) { fqmn = 8; fql = 8; }
    else {
      int bnd = min(a + 15, Tt - 1);
      fqmn = min(frame_of(a), frame_of(bnd));
      int t = a + l16;
      fql = (t >= Tt) ? 8 : frame_of(t);
    }
    Cmn[g] = min(137 + 196 * (fqmn + 1), Tt);   // wave-wide full-tile bound
    Ath[g] = fql + 2;                            // action keys: key < A
    Bth[g] = 9 + 16 * (fql + 1);                 // tactile keys: key < B
    Cth[g] = min(137 + 196 * (fql + 1), Tt);     // image keys: key < C
  }
  int limw = max(lim[0], lim[1]);
  int nktw = (limw + 63) >> 6;                  // this wave's needed tiles
  int k0t = (ch * nktw) / NCH;                  // balanced 2-way split
  int k1t = ((ch + 1) * nktw) / NCH;

  // Q fragments (once per wave)
  short8 qa[2][2];
  for (int g = 0; g < 2; g++) {
    const __hip_bfloat16* qr = qb + (size_t)(t0q + w * 32 + g * 16 + l16) * HD + grp * 8;
    qa[g][0] = *(const short8*)(qr);
    qa[g][1] = *(const short8*)(qr + 32);
  }
  f32x4 o[2][4];
  for (int g = 0; g < 2; g++)
    for (int jt = 0; jt < 4; jt++) { f32x4 z = {0.f,0.f,0.f,0.f}; o[g][jt] = z; }
  f32x4 ps[2];
  { f32x4 z = {0.f,0.f,0.f,0.f}; ps[0] = z; ps[1] = z; }

  const short8* kbase = (const short8*)(kpk + (size_t)bh * NKT_ALL * 4096);
  const short8* vbase = (const short8*)(vpk + (size_t)bh * NKT_ALL * 4096);

  for (int kt = k0t; kt < k1t; kt++) {
    const int t0k = kt * 64;
    const short8* kp = kbase + (size_t)kt * 512;
    const short8* vp = vbase + (size_t)kt * 512;
    short8 kf[4][2], vf[4][2];
    for (int j = 0; j < 4; j++)
      for (int hh = 0; hh < 2; hh++) kf[j][hh] = kp[(j * 2 + hh) * 64 + lane];
    for (int jt = 0; jt < 4; jt++)
      for (int kb2 = 0; kb2 < 2; kb2++) vf[jt][kb2] = vp[(jt * 2 + kb2) * 64 + lane];

    f32x4 s[2][4];
    for (int j = 0; j < 4; j++) {               // S^T = K * Q^T
      f32x4 z = {0.f,0.f,0.f,0.f};
      s[0][j] = MFMA16(kf[j][0], qa[0][0], z);
      s[0][j] = MFMA16(kf[j][1], qa[0][1], s[0][j]);
      s[1][j] = MFMA16(kf[j][0], qa[1][0], z);
      s[1][j] = MFMA16(kf[j][1], qa[1][1], s[1][j]);
    }

    bool act0 = t0k < lim[0], act1 = t0k < lim[1];
    bool fullk = (t0k + 64 <= Tt);
    S8u pf[2][2];
    for (int g = 0; g < 2; g++) {
      bool act = g == 0 ? act0 : act1;
      if (!act) continue;                       // wave-uniform
      bool needm = !(fullk && (t0k >= 192 ? (t0k + 64) <= Cmn[g] : Cmn[g] >= Tt));
      if (needm) {                              // threshold-compare mask
        for (int j = 0; j < 4; j++)
          for (int r = 0; r < 4; r++) {
            int key = t0k + j * 16 + grp * 4 + r;
            int thr = key < 9 ? Ath[g] : (key < 137 ? Bth[g] : Cth[g]);
            if (key >= thr) s[g][j][r] = -1e30f;
          }
      }
      f32x4 p[4];
      for (int j = 0; j < 4; j++)
        for (int r = 0; r < 4; r++) p[j][r] = ex2(s[g][j][r]);
      ps[g] += (p[0] + p[1]) + (p[2] + p[3]);   // deferred reduction
      pf[g][0].u[0] = pack2bf(p[0][0], p[0][1]);
      pf[g][0].u[1] = pack2bf(p[0][2], p[0][3]);
      pf[g][0].u[2] = pack2bf(p[1][0], p[1][1]);
      pf[g][0].u[3] = pack2bf(p[1][2], p[1][3]);
      pf[g][1].u[0] = pack2bf(p[2][0], p[2][1]);
      pf[g][1].u[1] = pack2bf(p[2][2], p[2][3]);
      pf[g][1].u[2] = pack2bf(p[3][0], p[3][1]);
      pf[g][1].u[3] = pack2bf(p[3][2], p[3][3]);
    }

    for (int jt = 0; jt < 4; jt++)              // O^T += V^T * P^T
      for (int kb2 = 0; kb2 < 2; kb2++) {
        if (act0) o[0][jt] = MFMA16(vf[jt][kb2], pf[0][kb2].v, o[0][jt]);
        if (act1) o[1][jt] = MFMA16(vf[jt][kb2], pf[1][kb2].v, o[1][jt]);
      }
  }

  // final softmax-denominator reduction (once, not per tile)
  float lr[2];
  for (int g = 0; g < 2; g++) {
    float sum = (ps[g][0] + ps[g][1]) + (ps[g][2] + ps[g][3]);
    sum += __shfl_xor(sum, 16);
    sum += __shfl_xor(sum, 32);
    lr[g] = sum;
  }

  // epilogue: unnormalized bf16 partials (always written, zeros if empty)
  const int blk = bh * (NQT * NCH) + cq;
  __hip_bfloat16* op = Opart + (size_t)blk * (128 * 64);
  for (int g = 0; g < 2; g++) {
    int row = w * 32 + g * 16 + l16;
    for (int jt = 0; jt < 4; jt++) {
      unsigned p01 = pack2bf(o[g][jt][0], o[g][jt][1]);
      unsigned p23 = pack2bf(o[g][jt][2], o[g][jt][3]);
      ushort4 u;
      u.x = p01 & 0xffff; u.y = p01 >> 16; u.z = p23 & 0xffff; u.w = p23 >> 16;
      *(ushort4*)(op + row * 64 + jt * 16 + grp * 4) = u;
    }
    if (grp == 0) lpart[(size_t)blk * 128 + w * 32 + g * 16 + l16] = lr[g];
  }
}

// sum NCH chunk partials, normalize, write y bf16
__global__ __launch_bounds__(256) void k_combine(const __hip_bfloat16* __restrict__ Opart,
                                                 const float* __restrict__ lpart,
                                                 __hip_bfloat16* __restrict__ y) {
  const int tid = threadIdx.x;
  const int qt = blockIdx.x, bh = blockIdx.y;
  const int b = bh / NH, h = bh - b * NH;
  const int t0q = qt * 128;
  const int blk0 = bh * (NQT * NCH) + qt * NCH;
  __shared__ float ls[128];
  if (tid < 128) {
    float s = 0.f;
    for (int c = 0; c < NCH; c++) s += lpart[(size_t)(blk0 + c) * 128 + tid];
    ls[tid] = (s > 0.f) ? 1.0f / s : 0.f;
  }
  __syncthreads();
  for (int it = 0; it < 4; it++) {
    int e8 = it * 256 + tid;                     // 8-elem group in [0,1024)
    int e = e8 * 8;
    int row = e >> 6, d = e & 63;
    int t = t0q + row;
    if (t >= Tt) continue;
    float acc[8] = {0,0,0,0,0,0,0,0};
    for (int c = 0; c < NCH; c++) {
      short8 vv = *(const short8*)(Opart + (size_t)(blk0 + c) * (128 * 64) + e);
      for (int i = 0; i < 8; i++) {
        union { unsigned u; float f; } cv;
        cv.u = ((unsigned)(unsigned short)vv[i]) << 16;
        acc[i] += cv.f;
      }
    }
    float rinv = ls[row];
    short8 outv;
    for (int i = 0; i < 8; i += 2) {
      unsigned p = pack2bf(acc[i] * rinv, acc[i + 1] * rinv);
      outv[i] = (short)(p & 0xffff);
      outv[i + 1] = (short)(p >> 16);
    }
    *(short8*)(y + (size_t)(b * Tt + t) * C_ + h * 64 + d) = outv;
  }
}

extern "C" void kernel_launch(void* const* d_in, const int* in_sizes, int n_in,
                              void* d_out, int out_size, void* d_ws, size_t ws_size,
                              hipStream_t stream) {
  const float* x  = (const float*)d_in[0];
  const float* Wa = (const float*)d_in[1];
  const float* Wp = (const float*)d_in[2];
  float* out = (float*)d_out;

  char* ws = (char*)d_ws;
  size_t off = 0;
  auto alloc = [&](size_t bytes) { size_t r = off; off += (bytes + 255) & ~(size_t)255; return r; };
  __hip_bfloat16* xb  = (__hip_bfloat16*)(ws + alloc((size_t)Mp * C_ * 2));
  __hip_bfloat16* wat = (__hip_bfloat16*)(ws + alloc((size_t)3 * C_ * C_ * 2));
  __hip_bfloat16* wpt = (__hip_bfloat16*)(ws + alloc((size_t)C_ * C_ * 2));
  __hip_bfloat16* qb  = (__hip_bfloat16*)(ws + alloc((size_t)Bb * NH * Tp * HD * 2));
  __hip_bfloat16* kpk = (__hip_bfloat16*)(ws + alloc((size_t)Bb * NH * NKT_ALL * 4096 * 2));
  __hip_bfloat16* vpk = (__hip_bfloat16*)(ws + alloc((size_t)Bb * NH * NKT_ALL * 4096 * 2));
  __hip_bfloat16* yb  = (__hip_bfloat16*)(ws + alloc((size_t)Mp * C_ * 2));
  __hip_bfloat16* Opart = (__hip_bfloat16*)(ws + alloc((size_t)Bb * NH * NQT * NCH * 128 * 64 * 2));
  float*          lpart = (float*)(ws + alloc((size_t)Bb * NH * NQT * NCH * 128 * 4));

  k_prep<<<PREP_CONV + PREP_TA + PREP_TB, 256, 0, stream>>>(x, xb, Wa, wat, Wp, wpt);
  k_gemm_qkv<<<dim3(Mp / 256, 3 * C_ / 256), 512, 0, stream>>>(xb, wat, qb, kpk, vpk);
  k_attn<<<dim3(Bb * NH * NQT * NCH), 256, 0, stream>>>(qb, kpk, vpk, Opart, lpart);
  k_combine<<<dim3(NQT, Bb * NH), 256, 0, stream>>>(Opart, lpart, yb);
  k_gemm_proj128<<<dim3(Mp / 128, C_ / 128), 256, 0, stream>>>(yb, wpt, out);
}